// Round 3
// baseline (126.190 us; speedup 1.0000x reference)
//
#include <hip/hip_runtime.h>

#define M_PAD 512

// Pass 1: run-boundary detection over the sorted ray_indices.
// start[r] = first index with ri[i]==r ; endx[r] = last+1.
// Rays never referenced keep start=endx=0 (memset) -> count 0.
__global__ void boundary_kernel(const int* __restrict__ ri,
                                int* __restrict__ start, int* __restrict__ endx,
                                int T) {
    int i = blockIdx.x * blockDim.x + threadIdx.x;
    if (i >= T) return;
    int r = ri[i];
    if (i == 0 || ri[i - 1] != r) start[r] = i;
    if (i == T - 1 || ri[i + 1] != r) endx[r] = i + 1;
}

// Pass 2 (fused): iterate the (N, 512) output space, 4 slots per thread.
// Valid slots gather i = start[r]+j (coalesced: consecutive j -> consecutive i),
// compute z/dist/xyz, and also write xyz_out[i] (bijective over [0,T)).
// Invalid slots produce zeros. Every output line written exactly once, fully,
// with 16B stores -> no partial-line RMW, no second pass.
__global__ void fused_kernel(const float* __restrict__ rays,
                             const float* __restrict__ ts,
                             const float* __restrict__ te,
                             const int* __restrict__ start,
                             const int* __restrict__ endx,
                             float* __restrict__ xyz_out,     // (T,4)
                             float* __restrict__ ray_valid,   // (N,512)
                             float* __restrict__ z_vals,      // (N,512)
                             float* __restrict__ dists,       // (N,512)
                             float* __restrict__ xyz_w,       // (N,512,4)
                             float* __restrict__ whole_valid, // (N,)
                             int total4) {
    int idx = blockIdx.x * blockDim.x + threadIdx.x;
    if (idx >= total4) return;
    int r = idx >> 7;                 // 128 threads per ray
    int q = (idx & 127) << 2;        // base slot j0, multiple of 4
    int s = start[r];
    int cnt = endx[r] - s;

    float4 z4, d4, v4;
    float* zp = &z4.x; float* dp = &d4.x; float* vp = &v4.x;
    float4 p[4];

    // ray origin+dir: uniform across the 128 threads of this ray -> L1 broadcast
    const float* rc = rays + (size_t)r * 6;
    float ox = rc[0], oy = rc[1], oz = rc[2];
    float dx = rc[3], dy = rc[4], dz = rc[5];

    #pragma unroll
    for (int e = 0; e < 4; ++e) {
        int j = q + e;
        bool valid = j < cnt;
        if (valid) {
            int i = s + j;
            float a = ts[i], b = te[i];
            float z = (a + b) * 0.5f;
            float dd = b - a;
            float4 pt = make_float4(fmaf(z, dx, ox), fmaf(z, dy, oy),
                                    fmaf(z, dz, oz), 0.0f);
            reinterpret_cast<float4*>(xyz_out)[i] = pt;
            zp[e] = z; dp[e] = dd; vp[e] = 1.0f; p[e] = pt;
        } else {
            zp[e] = 0.f; dp[e] = 0.f; vp[e] = 0.f;
            p[e] = make_float4(0.f, 0.f, 0.f, 0.f);
        }
    }

    size_t base = (size_t)r * M_PAD + q;
    *reinterpret_cast<float4*>(&z_vals[base])    = z4;
    *reinterpret_cast<float4*>(&dists[base])     = d4;
    *reinterpret_cast<float4*>(&ray_valid[base]) = v4;
    float4* xw = reinterpret_cast<float4*>(xyz_w) + base;
    xw[0] = p[0]; xw[1] = p[1]; xw[2] = p[2]; xw[3] = p[3];

    if (q == 0) whole_valid[r] = 1.0f;
}

extern "C" void kernel_launch(void* const* d_in, const int* in_sizes, int n_in,
                              void* d_out, int out_size, void* d_ws, size_t ws_size,
                              hipStream_t stream) {
    const float* rays = (const float*)d_in[0];  // (N,6)
    const int*   ri   = (const int*)d_in[1];    // (T,) sorted
    const float* ts   = (const float*)d_in[2];  // (T,)
    const float* te   = (const float*)d_in[3];  // (T,)
    const int N = in_sizes[0] / 6;
    const int T = in_sizes[1];

    float* out         = (float*)d_out;
    float* xyz_out     = out;                                    // T*4
    float* ray_valid   = xyz_out + (size_t)T * 4;                // N*512
    float* z_vals      = ray_valid + (size_t)N * M_PAD;          // N*512
    float* dists       = z_vals + (size_t)N * M_PAD;             // N*512
    float* whole_valid = dists + (size_t)N * M_PAD;              // N
    float* xyz_w       = whole_valid + N;                        // N*512*4

    int* start = (int*)d_ws;
    int* endx  = start + N;
    hipMemsetAsync(d_ws, 0, (size_t)2 * N * sizeof(int), stream);

    const int B = 256;
    boundary_kernel<<<(T + B - 1) / B, B, 0, stream>>>(ri, start, endx, T);
    const int total4 = N * (M_PAD / 4);
    fused_kernel<<<(total4 + B - 1) / B, B, 0, stream>>>(rays, ts, te, start, endx,
                                                         xyz_out, ray_valid, z_vals,
                                                         dists, xyz_w, whole_valid,
                                                         total4);
}

// Round 5
// 102.413 us; speedup vs baseline: 1.2322x; 1.2322x over previous
//
#include <hip/hip_runtime.h>

#define M_PAD 512

// Pass 1: run-boundary detection over the sorted ray_indices.
// start[r] = first index with ri[i]==r ; endx[r] = last+1.
// Rays never referenced keep start=endx=0 (memset) -> count 0.
__global__ void boundary_kernel(const int* __restrict__ ri,
                                int* __restrict__ start, int* __restrict__ endx,
                                int T) {
    int i = blockIdx.x * blockDim.x + threadIdx.x;
    if (i >= T) return;
    int r = ri[i];
    if (i == 0 || ri[i - 1] != r) start[r] = i;
    if (i == T - 1 || ri[i + 1] != r) endx[r] = i + 1;
}

// Pass 2 (fused, ONE slot per thread): iterate the (N, 512) output space.
// Valid slots gather i = start[r]+j (consecutive lanes -> consecutive i, dense),
// compute z/dist/xyz, write xyz_out[i] (bijection onto [0,T)).
// All stores are lane-consecutive: 4B scalars and 16B float4 -> one dense
// line-sweep per buffer, no partial-line RMW, no strided store pathology.
__global__ void fused_kernel(const float* __restrict__ rays,
                             const float* __restrict__ ts,
                             const float* __restrict__ te,
                             const int* __restrict__ start,
                             const int* __restrict__ endx,
                             float* __restrict__ xyz_out,     // (T,4)
                             float* __restrict__ ray_valid,   // (N,512)
                             float* __restrict__ z_vals,      // (N,512)
                             float* __restrict__ dists,       // (N,512)
                             float* __restrict__ xyz_w,       // (N,512,4)
                             float* __restrict__ whole_valid, // (N,)
                             int total) {
    int idx = blockIdx.x * blockDim.x + threadIdx.x;
    if (idx >= total) return;
    int r = idx >> 9;            // 512 slots per ray; wave64 = 1/8 ray (uniform r)
    int j = idx & (M_PAD - 1);
    int s = start[r];
    int cnt = endx[r] - s;

    float z = 0.0f, dd = 0.0f, v = 0.0f;
    float4 pt = make_float4(0.f, 0.f, 0.f, 0.f);

    if (j < cnt) {
        int i = s + j;
        float a = ts[i], b = te[i];
        z  = (a + b) * 0.5f;
        dd = b - a;
        v  = 1.0f;
        const float* rc = rays + (size_t)r * 6;   // wave-uniform -> L1 broadcast
        pt = make_float4(fmaf(z, rc[3], rc[0]),
                         fmaf(z, rc[4], rc[1]),
                         fmaf(z, rc[5], rc[2]), 0.0f);
        reinterpret_cast<float4*>(xyz_out)[i] = pt;   // dense: lane i consecutive
    }

    z_vals[idx]    = z;
    dists[idx]     = dd;
    ray_valid[idx] = v;
    reinterpret_cast<float4*>(xyz_w)[idx] = pt;       // dense: 16B/lane consecutive

    if (j == 0) whole_valid[r] = 1.0f;
}

extern "C" void kernel_launch(void* const* d_in, const int* in_sizes, int n_in,
                              void* d_out, int out_size, void* d_ws, size_t ws_size,
                              hipStream_t stream) {
    const float* rays = (const float*)d_in[0];  // (N,6)
    const int*   ri   = (const int*)d_in[1];    // (T,) sorted
    const float* ts   = (const float*)d_in[2];  // (T,)
    const float* te   = (const float*)d_in[3];  // (T,)
    const int N = in_sizes[0] / 6;
    const int T = in_sizes[1];

    float* out         = (float*)d_out;
    float* xyz_out     = out;                                    // T*4
    float* ray_valid   = xyz_out + (size_t)T * 4;                // N*512
    float* z_vals      = ray_valid + (size_t)N * M_PAD;          // N*512
    float* dists       = z_vals + (size_t)N * M_PAD;             // N*512
    float* whole_valid = dists + (size_t)N * M_PAD;              // N
    float* xyz_w       = whole_valid + N;                        // N*512*4

    int* start = (int*)d_ws;
    int* endx  = start + N;
    hipMemsetAsync(d_ws, 0, (size_t)2 * N * sizeof(int), stream);

    const int B = 256;
    boundary_kernel<<<(T + B - 1) / B, B, 0, stream>>>(ri, start, endx, T);
    const int total = N * M_PAD;
    fused_kernel<<<(total + B - 1) / B, B, 0, stream>>>(rays, ts, te, start, endx,
                                                        xyz_out, ray_valid, z_vals,
                                                        dists, xyz_w, whole_valid,
                                                        total);
}